// Round 8
// baseline (199.940 us; speedup 1.0000x reference)
//
#include <hip/hip_runtime.h>
#include <math.h>

static constexpr int kM = 80;
static constexpr int kT = 4000;
static constexpr int kB = 64;
static constexpr int kLow = kM / 3;                 // 26
static constexpr int kHighStart = 2 * kM / 3;       // 53
static constexpr int kHighCount = kM - kHighStart;  // 27
static constexpr int kC = 256;      // emit cols per block
static constexpr int kW = 256;      // warmup cols (err <= 0.95^256 ~ 2e-6)
static constexpr int kWin = kC + kW;// 512-col scan window
static constexpr int kE = 8;        // elems per lane: 64*8 = 512
static constexpr int kChunks = 16;  // 16*256 = 4096 >= 4000
#define EPSF 1e-6f
#define LOG2E 1.4426950408889634f

typedef float vfloat4 __attribute__((ext_vector_type(4)));
typedef float vfloat2 __attribute__((ext_vector_type(2)));

__device__ __forceinline__ float hw_exp2(float x) { return __builtin_amdgcn_exp2f(x); }
__device__ __forceinline__ float hw_log2(float x) { return __builtin_amdgcn_logf(x); }
__device__ __forceinline__ float fast_sigmoid(float x) {
    return __builtin_amdgcn_rcpf(1.0f + hw_exp2(-x * LOG2E));
}

// Fused gate + dual-PCEN, v2.
// Grid (16 chunks, 64 b) = 1024 blocks x 256 thr (4 waves) -> 4 blocks/CU.
// Phase 0: threads 0..79 stage per-channel params into LDS.
// Phase 1: wave w accumulates channels [20w,20w+20) gate-sums for 64 col-quads
//          (float4 loads, register sums); LDS reduce; wave 0 finalizes gate_s.
// Phase 2: wave w scans 20 rows over window [ws,ws+512) (emit [c0,c0+256)).
//          IIR replay (pk_fma only) compacts (sm,x) for emit cols into LDS;
//          then ALL 64 lanes run the 8-trans PCEN math on 4 cols each (dense
//          trans issue) and store coalesced. Same-wave LDS -> no barrier.
__global__ __launch_bounds__(256, 4) void fused_kernel(
    const float* __restrict__ mel,
    const float* __restrict__ ls_ns, const float* __restrict__ la_ns,
    const float* __restrict__ ld_ns, const float* __restrict__ lr_ns,
    const float* __restrict__ ls_st, const float* __restrict__ la_st,
    const float* __restrict__ ld_st, const float* __restrict__ lr_st,
    const float* __restrict__ gate_temp,
    float* __restrict__ out)
{
    const int j    = blockIdx.x;         // t-chunk
    const int b    = blockIdx.y;
    const int c0   = j * kC;
    const int tid  = threadIdx.x;
    const int lane = tid & 63;
    const int wid  = tid >> 6;

    __shared__ vfloat4 redu[4][4][64];   // 16 KB  phase-1 partials
    __shared__ float   gate_s[kC];       // 1 KB
    __shared__ vfloat4 prm[kM][3];       // 3.75 KB
    __shared__ vfloat2 c_sm[4][kE][32];  // 8 KB   per-wave compaction (sm pairs)
    __shared__ float   c_x[4][kE][32];   // 4 KB   per-wave compaction (x)

    // ---------- phase 0: per-channel params ----------
    if (tid < kM) {
        const int m = tid;
        const float s_ns     = fminf(fmaxf(fast_sigmoid(ls_ns[m]), 0.05f), 0.3f);
        const float alpha_ns = fminf(fmaxf(fast_sigmoid(la_ns[m]), 0.9f), 0.999f);
        const float delta_ns = fminf(fmaxf(hw_exp2(ld_ns[m] * LOG2E), 0.5f), 5.0f);
        const float r_ns     = fminf(fmaxf(fast_sigmoid(lr_ns[m]), 0.05f), 0.25f);
        const float s_st     = fminf(fmaxf(fast_sigmoid(ls_st[m]), 0.05f), 0.3f);
        const float alpha_st = fminf(fmaxf(fast_sigmoid(la_st[m]), 0.9f), 0.999f);
        const float delta_st = fminf(fmaxf(hw_exp2(ld_st[m] * LOG2E), 0.001f), 0.1f);
        const float r_st     = fminf(fmaxf(fast_sigmoid(lr_st[m]), 0.05f), 0.25f);
        vfloat4 w0; w0.x = 1.0f - s_ns; w0.y = 1.0f - s_st; w0.z = s_ns; w0.w = s_st;
        vfloat4 w1; w1.x = delta_ns; w1.y = delta_st; w1.z = -alpha_ns; w1.w = -alpha_st;
        vfloat4 w2; w2.x = r_ns; w2.y = r_st;
        w2.z = hw_exp2(r_ns * hw_log2(delta_ns));   // delta^r
        w2.w = hw_exp2(r_st * hw_log2(delta_st));
        prm[m][0] = w0; prm[m][1] = w1; prm[m][2] = w2;
    }

    // ---------- phase 1: gate partial sums (wave w -> channels 20w..20w+19) --
    {
        const int qcol = c0 + 4 * lane;              // quad start col
        vfloat4 slog = {0.f,0.f,0.f,0.f}, ssum = {0.f,0.f,0.f,0.f};
        vfloat4 slow = {0.f,0.f,0.f,0.f}, shigh = {0.f,0.f,0.f,0.f};
        if (qcol < kT) {                             // kT%4==0 -> whole quad ok
            const float* base = mel + (size_t)b * kM * kT + qcol;
            const int m0 = wid * 20;
            #pragma unroll
            for (int jj = 0; jj < 20; ++jj) {
                const int m = m0 + jj;
                const vfloat4 v = *reinterpret_cast<const vfloat4*>(base + (size_t)m * kT);
                vfloat4 lg;
                lg.x = hw_log2(v.x + 1e-8f); lg.y = hw_log2(v.y + 1e-8f);
                lg.z = hw_log2(v.z + 1e-8f); lg.w = hw_log2(v.w + 1e-8f);
                slog += lg;
                ssum += v;
                if (m < kLow)        slow  += v;     // wave-uniform
                if (m >= kHighStart) shigh += v;
            }
        }
        redu[wid][0][lane] = slog;
        redu[wid][1][lane] = ssum;
        redu[wid][2][lane] = slow;
        redu[wid][3][lane] = shigh;
    }
    __syncthreads();

    if (wid == 0) {
        const int qcol = c0 + 4 * lane;
        if (qcol < kT) {
            const vfloat4 slog  = redu[0][0][lane] + redu[1][0][lane] + redu[2][0][lane] + redu[3][0][lane];
            const vfloat4 ssum  = redu[0][1][lane] + redu[1][1][lane] + redu[2][1][lane] + redu[3][1][lane];
            const vfloat4 slow  = redu[0][2][lane] + redu[1][2][lane] + redu[2][2][lane] + redu[3][2][lane];
            const vfloat4 shigh = redu[0][3][lane] + redu[1][3][lane] + redu[2][3][lane] + redu[3][3][lane];
            const float gt = gate_temp[0];
            const float sl[4] = {slog.x, slog.y, slog.z, slog.w};
            const float ss[4] = {ssum.x, ssum.y, ssum.z, ssum.w};
            const float lo[4] = {slow.x, slow.y, slow.z, slow.w};
            const float hi[4] = {shigh.x, shigh.y, shigh.z, shigh.w};
            vfloat4 o;
            #pragma unroll
            for (int q = 0; q < 4; ++q) {
                const float geo   = hw_exp2(sl[q] * (1.0f / kM));
                const float arith = ss[q] * (1.0f / kM) + 1e-8f;
                float sf = geo * __builtin_amdgcn_rcpf(arith);
                sf = fminf(fmaxf(sf, 0.0f), 1.0f);
                const float low  = lo[q] * (1.0f / kLow);
                const float high = hi[q] * (1.0f / kHighCount);
                float tilt = low * __builtin_amdgcn_rcpf(low + high + 1e-8f);
                tilt = fminf(fmaxf(tilt, 0.0f), 1.0f);
                const float sfa = sf + (1.0f - sf) * fmaxf(tilt - 0.6f, 0.0f);
                o[q] = fast_sigmoid(gt * (sfa - 0.5f));
            }
            *reinterpret_cast<vfloat4*>(gate_s + 4 * lane) = o;
        }
    }
    __syncthreads();

    // ---------- phase 2: dual PCEN scan, 20 rows per wave ----------
    const int ws = (j == 0) ? 0 : (c0 - kW);
    const int base_col = ws + lane * kE;
    const bool xvalid = (base_col + kE <= kT);       // whole-lane OOB only
    const int col4 = c0 + 4 * lane;                  // dense-pass cols
    const bool dvalid = (col4 < kT);

    for (int i = 0; i < 20; ++i) {
        const int m = wid * 20 + i;
        const vfloat4 w0 = prm[m][0];
        const vfloat4 w1 = prm[m][1];
        const vfloat4 w2 = prm[m][2];
        const vfloat2 a2 = {w0.x, w0.y};
        const vfloat2 s2 = {w0.z, w0.w};
        const vfloat2 d2 = {w1.x, w1.y};
        const float man = w1.z, mas = w1.w;
        const float r_ns = w2.x, r_st = w2.y, dr_ns = w2.z, dr_st = w2.w;
        const size_t rowoff = (size_t)(b * kM + m) * kT;

        float x[kE];
        if (xvalid) {
            const vfloat4* rp = reinterpret_cast<const vfloat4*>(mel + rowoff + base_col);
            const vfloat4 v0q = rp[0];
            const vfloat4 v1q = rp[1];
            x[0] = v0q.x; x[1] = v0q.y; x[2] = v0q.z; x[3] = v0q.w;
            x[4] = v1q.x; x[5] = v1q.y; x[6] = v1q.z; x[7] = v1q.w;
        } else {
            #pragma unroll
            for (int k = 0; k < kE; ++k) x[k] = 0.0f;
        }

        // local affine over 8 elems: v -> A*v + B ; A = a^8
        vfloat2 Bv = {0.0f, 0.0f};
        #pragma unroll
        for (int k = 0; k < kE; ++k) Bv = a2 * Bv + s2 * x[k];
        const vfloat2 p2 = a2 * a2;
        const vfloat2 p4 = p2 * p2;
        vfloat2 Av = p4 * p4;                        // a^8

        // inclusive Hillis-Steele composition scan across the wave
        #pragma unroll
        for (int d = 1; d < 64; d <<= 1) {
            const float qAn = __shfl_up(Av.x, d);
            const float qAs = __shfl_up(Av.y, d);
            const float qBn = __shfl_up(Bv.x, d);
            const float qBs = __shfl_up(Bv.y, d);
            if (lane >= d) {
                const vfloat2 qA = {qAn, qAs};
                const vfloat2 qB = {qBn, qBs};
                Bv = Av * qB + Bv;
                Av = Av * qA;
            }
        }

        // exclusive prefix + carry v0 = x[ws] (exact for j==0)
        vfloat2 eA, eB;
        eA.x = __shfl_up(Av.x, 1); eA.y = __shfl_up(Av.y, 1);
        eB.x = __shfl_up(Bv.x, 1); eB.y = __shfl_up(Bv.y, 1);
        if (lane == 0) { eA = (vfloat2){1.0f, 1.0f}; eB = (vfloat2){0.0f, 0.0f}; }
        const float x0 = __shfl(x[0], 0);
        const vfloat2 v0 = {x0, x0};
        vfloat2 sm = eA * v0 + eB;

        // replay (pk_fma only) + compact emit cols into LDS
        #pragma unroll
        for (int k = 0; k < kE; ++k) {
            sm = a2 * sm + s2 * x[k];                // v_pk_fma_f32
            const int e = base_col + k - c0;         // emit index
            if (e >= 0 && e < kC) {
                c_sm[wid][e & 7][e >> 3] = sm;
                c_x[wid][e & 7][e >> 3]  = x[k];
            }
        }

        // dense trans pass: 4 emit cols per lane, full exec mask
        if (dvalid) {
            const vfloat4 g4 = *reinterpret_cast<const vfloat4*>(gate_s + 4 * lane);
            vfloat4 r4;
            #pragma unroll
            for (int kk = 0; kk < 4; ++kk) {
                const int e = 4 * lane + kk;
                const vfloat2 smv = c_sm[wid][e & 7][e >> 3];
                const float  xv   = c_x[wid][e & 7][e >> 3];
                vfloat2 g2;
                g2.x = hw_exp2(man * hw_log2(smv.x + EPSF));
                g2.y = hw_exp2(mas * hw_log2(smv.y + EPSF));
                const vfloat2 u2 = g2 * xv + d2;     // v_pk_fma_f32
                const float on = hw_exp2(r_ns * hw_log2(u2.x)) - dr_ns;
                const float os = hw_exp2(r_st * hw_log2(u2.y)) - dr_st;
                r4[kk] = fmaf(g4[kk], os - on, on);
            }
            *reinterpret_cast<vfloat4*>(out + rowoff + col4) = r4;
        }
    }
}

extern "C" void kernel_launch(void* const* d_in, const int* in_sizes, int n_in,
                              void* d_out, int out_size, void* d_ws, size_t ws_size,
                              hipStream_t stream)
{
    const float* mel       = (const float*)d_in[0];
    const float* ls_ns     = (const float*)d_in[1];
    const float* la_ns     = (const float*)d_in[2];
    const float* ld_ns     = (const float*)d_in[3];
    const float* lr_ns     = (const float*)d_in[4];
    const float* ls_st     = (const float*)d_in[5];
    const float* la_st     = (const float*)d_in[6];
    const float* ld_st     = (const float*)d_in[7];
    const float* lr_st     = (const float*)d_in[8];
    const float* gate_temp = (const float*)d_in[9];
    float* out  = (float*)d_out;

    dim3 g(kChunks, kB);                 // 1024 blocks x 256 threads
    fused_kernel<<<g, 256, 0, stream>>>(mel, ls_ns, la_ns, ld_ns, lr_ns,
                                        ls_st, la_st, ld_st, lr_st,
                                        gate_temp, out);
}